// Round 8
// baseline (615.754 us; speedup 1.0000x reference)
//
#include <hip/hip_runtime.h>
#include <cstdint>

#define DEVINL __device__ __forceinline__

typedef uint16_t u16;
typedef uint32_t u32;
typedef uint64_t u64;
typedef __attribute__((ext_vector_type(8))) short short8;
typedef __attribute__((ext_vector_type(4))) float floatx4;
typedef __attribute__((ext_vector_type(4))) u32 u32x4;
typedef __attribute__((ext_vector_type(2))) u32 u32x2;
typedef const __attribute__((address_space(1))) void* gas_ptr;
typedef __attribute__((address_space(3))) void* las_ptr;

DEVINL u16 f2bf(float f) {
  u32 u = __float_as_uint(f);
  u32 r = u + 0x7FFFu + ((u >> 16) & 1u);   // RNE
  return (u16)(r >> 16);
}
DEVINL float bf2f(u16 b) { return __uint_as_float((u32)b << 16); }
DEVINL float bf_lo(u32 u) { return __uint_as_float(u << 16); }
DEVINL float bf_hi(u32 u) { return __uint_as_float(u & 0xFFFF0000u); }

// ---------- row_start[n] = lower_bound(dst, n) over sorted dst ----------
__global__ void rowstart_kernel(const int* __restrict__ dst, int* __restrict__ rs,
                                int N, int E) {
  int n = blockIdx.x * blockDim.x + threadIdx.x;
  if (n > N) return;
  int lo = 0, hi = E;
  while (lo < hi) { int mid = (lo + hi) >> 1; if (dst[mid] < n) lo = mid + 1; else hi = mid; }
  rs[n] = lo;
}

__global__ void zero_kernel(float* __restrict__ p, int n) {
  int i = blockIdx.x * blockDim.x + threadIdx.x;
  if (i < n) p[i] = 0.f;
}

// ---------- f32 -> 2-plane split-bf16: A'=[hi|lo], B'=[hi|hi], row len 2K ----------
template<bool IsA>
__global__ __launch_bounds__(256)
void split_kernel(const float* __restrict__ in, u16* __restrict__ out, int MK, int K) {
  int idx = blockIdx.x * blockDim.x + threadIdx.x;
  if (idx >= MK) return;
  int m = idx / K, k = idx - m * K;
  float a = in[idx];
  u16 h = f2bf(a);
  size_t base = (size_t)m * 2 * K;
  if (IsA) {
    u16 lo = f2bf(a - bf2f(h));
    out[base + k] = h;  out[base + K + k] = lo;
  } else {
    out[base + k] = h;  out[base + K + k] = h;
  }
}

// ---------- GEMM: C[M,Nout] = A'[M,K'] * B'[Nout,K']^T  (split-bf16 in) ----------
// OUTM: 1 = bf16 store, 2 = f32 atomicAdd (split-K: blockIdx.x indexes K-chunk).
template<int BN, int OUTM>
__global__ __launch_bounds__(256)
void gemm_bt_kernel(const u16* __restrict__ A, const u16* __restrict__ B,
                    float* __restrict__ Cf, u16* __restrict__ Cb,
                    int M, int Nout, int K, int kLen)
{
  constexpr int BM = 128, BK = 32, CF = BN / 16;
  constexpr int BCALLS = (BN * BK) / 512;          // 8/4/2 for BN=128/64/32
  __shared__ __align__(16) u16 As[BM * BK];
  __shared__ __align__(16) u16 Bs[BN * BK];
  const int tid  = threadIdx.x;
  const int wave = tid >> 6;
  const int lane = tid & 63;
  const int quad = lane >> 4;
  const int l16  = lane & 15;
  const int rowBase = blockIdx.y * BM;
  const int colBase = (OUTM == 2) ? 0 : blockIdx.x * BN;
  const int kStart  = (OUTM == 2) ? blockIdx.x * kLen : 0;

  floatx4 acc[2][CF];
  #pragma unroll
  for (int r = 0; r < 2; ++r)
    #pragma unroll
    for (int c = 0; c < CF; ++c)
      acc[r][c] = (floatx4){0.f, 0.f, 0.f, 0.f};

  int aRow[2], aCol[2];
  #pragma unroll
  for (int i = 0; i < 2; ++i) {
    int call = wave + 4 * i;
    int flat = call * 512 + lane * 8;
    int r = flat >> 5;
    aCol[i] = flat & 31;
    int gr = rowBase + r;
    if (gr >= M) gr = M - 1;
    aRow[i] = gr;
  }
  int bRow[2] = {0, 0}, bCol[2] = {0, 0};
  #pragma unroll
  for (int i = 0; i < 2; ++i) {
    int call = wave + 4 * i;
    if (call < BCALLS) {
      int flat = call * 512 + lane * 8;
      bRow[i] = colBase + (flat >> 5);
      bCol[i] = flat & 31;
    }
  }

  for (int k0 = kStart; k0 < kStart + kLen; k0 += BK) {
    __syncthreads();
    #pragma unroll
    for (int i = 0; i < 2; ++i) {
      int call = wave + 4 * i;
      const u16* gp = A + (size_t)aRow[i] * K + (k0 + aCol[i]);
      __builtin_amdgcn_global_load_lds((gas_ptr)gp,
          (las_ptr)(As + call * 512), 16, 0, 0);
    }
    #pragma unroll
    for (int i = 0; i < 2; ++i) {
      int call = wave + 4 * i;
      if (call < BCALLS) {
        const u16* gp = B + (size_t)bRow[i] * K + (k0 + bCol[i]);
        __builtin_amdgcn_global_load_lds((gas_ptr)gp,
            (las_ptr)(Bs + call * 512), 16, 0, 0);
      }
    }
    __syncthreads();
    short8 a0 = *(const short8*)(As + (32 * wave + l16) * BK + quad * 8);
    short8 a1 = *(const short8*)(As + (32 * wave + 16 + l16) * BK + quad * 8);
    #pragma unroll
    for (int c = 0; c < CF; ++c) {
      short8 b = *(const short8*)(Bs + (16 * c + l16) * BK + quad * 8);
      acc[0][c] = __builtin_amdgcn_mfma_f32_16x16x32_bf16(a0, b, acc[0][c], 0, 0, 0);
      acc[1][c] = __builtin_amdgcn_mfma_f32_16x16x32_bf16(a1, b, acc[1][c], 0, 0, 0);
    }
  }

  // C/D layout: col = lane&15, row = quad*4 + reg (verified m89/m91)
  #pragma unroll
  for (int rt = 0; rt < 2; ++rt)
    #pragma unroll
    for (int c = 0; c < CF; ++c)
      #pragma unroll
      for (int i = 0; i < 4; ++i) {
        int gr = rowBase + 32 * wave + 16 * rt + quad * 4 + i;
        if (gr < M) {
          int gc = colBase + 16 * c + l16;
          if (OUTM == 1) Cb[(size_t)gr * Nout + gc] = f2bf(acc[rt][c][i]);
          else           atomicAdd(Cf + (size_t)gr * Nout + gc, acc[rt][c][i]);
        }
      }
}

// ---------- el/er from bf16 z (H=8, F=64) ----------
__global__ __launch_bounds__(256)
void elr_bf16_kernel(const u16* __restrict__ z, const float* __restrict__ al,
                     const float* __restrict__ ar, float* __restrict__ el,
                     float* __restrict__ er, int N)
{
  int t = blockIdx.x * blockDim.x + threadIdx.x;
  if (t >= N * 8) return;
  int h = t & 7;
  const u32x4* zp = (const u32x4*)(z + (size_t)t * 64);
  const float* alp = al + h * 64;
  const float* arp = ar + h * 64;
  float sl = 0.f, sr = 0.f;
  #pragma unroll
  for (int i = 0; i < 8; ++i) {
    u32x4 zz = zp[i];
    #pragma unroll
    for (int j = 0; j < 4; ++j) {
      float z0 = bf_lo(zz[j]), z1 = bf_hi(zz[j]);
      int f = i * 8 + 2 * j;
      sl += z0 * alp[f] + z1 * alp[f + 1];
      sr += z0 * arp[f] + z1 * arp[f + 1];
    }
  }
  el[t] = sl;
  er[t] = sr;
}

// ---------- f32 elr (layer 3, H=1, F=32) ----------
template<int H, int F>
__global__ __launch_bounds__(256)
void elr_kernel(const float* __restrict__ z, const float* __restrict__ al,
                const float* __restrict__ ar, float* __restrict__ el,
                float* __restrict__ er, int N)
{
  int t = blockIdx.x * blockDim.x + threadIdx.x;
  if (t >= N * H) return;
  int h = t % H;
  const float4* zp  = (const float4*)(z + (size_t)t * F);
  const float4* alp = (const float4*)(al + h * F);
  const float4* arp = (const float4*)(ar + h * F);
  float sl = 0.f, sr = 0.f;
  #pragma unroll
  for (int i = 0; i < F / 4; ++i) {
    float4 zz = zp[i], aa = alp[i], rr = arp[i];
    sl += zz.x * aa.x + zz.y * aa.y + zz.z * aa.z + zz.w * aa.w;
    sr += zz.x * rr.x + zz.y * rr.y + zz.z * rr.z + zz.w * rr.w;
  }
  el[t] = sl;
  er[t] = sr;
}

// ---------- fused edge records, head-major: edata[h][e] = {src, alpha} (8 B) ----------
// One thread per (node, head). Shift-free softmax (logits O(1), no overflow).
__global__ __launch_bounds__(256)
void alpha_kernel(const float* __restrict__ el, const float* __restrict__ er,
                  const int* __restrict__ src, const int* __restrict__ rs,
                  u32* __restrict__ edata, int N, int E)
{
  int t = blockIdx.x * blockDim.x + threadIdx.x;
  if (t >= N * 8) return;
  int n = t >> 3, h = t & 7;
  int s = rs[n], e = rs[n + 1];
  float ern = er[t];
  float den = 0.f;
  const size_t hE2 = (size_t)h * E * 2;
  for (int k = s; k < e; ++k) {
    int si = src[k];
    float v = el[si * 8 + h] + ern;
    v = (v > 0.f) ? v : 0.2f * v;          // leaky_relu 0.2
    float wv = __expf(v);
    den += wv;
    u32x2 ed;
    ed[0] = (u32)si;
    ed[1] = __float_as_uint(wv);
    *(u32x2*)(edata + hE2 + (size_t)k * 2) = ed;
  }
  float inv = 1.f / den;
  for (int k = s; k < e; ++k) {
    u32* ap = edata + hE2 + (size_t)k * 2 + 1;
    *ap = __float_as_uint(__uint_as_float(*ap) * inv);
  }
}

// ---------- normalized edge attention, H=1 (layer 3) ----------
__global__ __launch_bounds__(256)
void alpha1_kernel(const float* __restrict__ el, const float* __restrict__ er,
                   const int* __restrict__ src, const int* __restrict__ rs,
                   float* __restrict__ alpha, int N)
{
  int n = blockIdx.x * blockDim.x + threadIdx.x;
  if (n >= N) return;
  int s = rs[n], e = rs[n + 1];
  float ern = er[n];
  float den = 0.f;
  for (int k = s; k < e; ++k) {
    float v = el[src[k]] + ern;
    v = (v > 0.f) ? v : 0.2f * v;
    float wv = __expf(v);
    den += wv;
    alpha[k] = wv;
  }
  float inv = 1.f / den;
  for (int k = s; k < e; ++k) alpha[k] *= inv;
}

// ---------- layers 1/2 aggregate, XCD-sliced, fused edge records ----------
// block = (node, head); head = blockIdx.x & 7 -> one XCD per head slice
// (z slice 3.2 MB + edata plane 3.2 MB, both L2-resident per XCD).
// 64 threads: q = tid>>4 edge offset (unroll 2 -> 8 edges in flight),
// c = tid&15 col group (4 bf16 = 8 B/lane).
// Hot loop per edge: 1 u32x2 broadcast (src+alpha), 1 z gather, 4 unpack-fma.
__global__ __launch_bounds__(64)
void agg_sliced_kernel(const u16* __restrict__ z, const u32* __restrict__ edata,
                       const int* __restrict__ rs, u16* __restrict__ a2out, int E)
{
  const int bid = blockIdx.x;
  const int h = bid & 7;                 // slice == head == XCD
  const int n = bid >> 3;
  const int tid = threadIdx.x;
  const int q = tid >> 4;                // edge offset within group of 4
  const int c = tid & 15;                // col group: 4 bf16 cols = 8 B
  const int s = rs[n], e = rs[n + 1];
  const u16* zs = z + h * 64 + 4 * c;    // this lane's column base
  const u32* eb = edata + (size_t)h * E * 2;

  float a0 = 0.f, a1 = 0.f, a2 = 0.f, a3 = 0.f;

  for (int k0 = s; k0 < e; k0 += 8) {
    #pragma unroll
    for (int j = 0; j < 2; ++j) {
      int k = k0 + q + 4 * j;
      int kc = min(k, e - 1);            // clamp: safe load, zero weight
      u32x2 ed = *(const u32x2*)(eb + (size_t)kc * 2);   // broadcast {src, alpha}
      int si = (int)ed[0];
      float aw = (k < e) ? __uint_as_float(ed[1]) : 0.f;
      u32x2 zz = *(const u32x2*)(zs + (size_t)si * 512); // L2-hit gather
      a0 += aw * bf_lo(zz[0]);
      a1 += aw * bf_hi(zz[0]);
      a2 += aw * bf_lo(zz[1]);
      a3 += aw * bf_hi(zz[1]);
    }
  }

  // combine the 4 edge-quarters
  a0 += __shfl_xor(a0, 16); a0 += __shfl_xor(a0, 32);
  a1 += __shfl_xor(a1, 16); a1 += __shfl_xor(a1, 32);
  a2 += __shfl_xor(a2, 16); a2 += __shfl_xor(a2, 32);
  a3 += __shfl_xor(a3, 16); a3 += __shfl_xor(a3, 32);

  if (tid < 16) {
    float o[4] = {a0, a1, a2, a3};       // already normalized; deg==0 -> 0
    u32x2 hp, lp;
    #pragma unroll
    for (int j = 0; j < 2; ++j) {
      float o0 = o[2 * j], o1 = o[2 * j + 1];
      o0 = (o0 > 0.f) ? o0 : (__expf(o0) - 1.f);   // elu
      o1 = (o1 > 0.f) ? o1 : (__expf(o1) - 1.f);
      u16 h0 = f2bf(o0), h1 = f2bf(o1);
      u16 l0 = f2bf(o0 - bf2f(h0)), l1 = f2bf(o1 - bf2f(h1));
      hp[j] = ((u32)h1 << 16) | h0;
      lp[j] = ((u32)l1 << 16) | l0;
    }
    u16* row = a2out + (size_t)n * 1024 + h * 64 + 4 * c;  // A' = [hi|lo]
    *(u32x2*)row = hp;
    *(u32x2*)(row + 512) = lp;
  }
}

// ---------- layer 3 aggregate: f32 z3 (3.2 MB), alpha-precomputed ----------
__global__ __launch_bounds__(64)
void agg3_kernel(const float* __restrict__ z, const float* __restrict__ alpha,
                 const int* __restrict__ src, const int* __restrict__ rs,
                 float* __restrict__ out)
{
  const int n = blockIdx.x, tid = threadIdx.x;
  const int q = tid >> 5, c = tid & 31;
  const int s = rs[n], e = rs[n + 1];
  float acc = 0.f;

  for (int k0 = s; k0 < e; k0 += 4) {
    #pragma unroll
    for (int j = 0; j < 2; ++j) {
      int k = k0 + q + 2 * j;
      int kc = min(k, e - 1);
      int si = src[kc];
      float aw = alpha[kc];
      aw = (k < e) ? aw : 0.f;
      acc += aw * z[(size_t)si * 32 + c];
    }
  }
  acc += __shfl_xor(acc, 32);
  if (tid < 32) out[(size_t)n * 32 + tid] = acc;   // deg==0 -> 0
}

extern "C" void kernel_launch(void* const* d_in, const int* in_sizes, int n_in,
                              void* d_out, int out_size, void* d_ws, size_t ws_size,
                              hipStream_t stream)
{
  constexpr int N = 25000, E = 400000, K1 = 256, HF = 512, CLS = 32;
  const float* h   = (const float*)d_in[0];
  const int*   src = (const int*)d_in[1];
  const int*   dst = (const int*)d_in[2];
  const float* W1  = (const float*)d_in[3];
  const float* al1 = (const float*)d_in[4];
  const float* ar1 = (const float*)d_in[5];
  const float* W2  = (const float*)d_in[6];
  const float* al2 = (const float*)d_in[7];
  const float* ar2 = (const float*)d_in[8];
  const float* W3  = (const float*)d_in[9];
  const float* al3 = (const float*)d_in[10];
  const float* ar3 = (const float*)d_in[11];
  float* out = (float*)d_out;

  char* w = (char*)d_ws;
  auto take = [&](size_t bytes) {
    char* p = w;
    w += (bytes + 255) & ~(size_t)255;
    return p;
  };
  int*   rs     = (int*)  take((size_t)(N + 1) * sizeof(int));
  float* el     = (float*)take((size_t)N * 8 * sizeof(float));
  float* er     = (float*)take((size_t)N * 8 * sizeof(float));
  float* z3     = (float*)take((size_t)N * CLS * sizeof(float));     // 3.2 MB
  u32*   edata  = (u32*)  take((size_t)E * 8 * 2 * sizeof(u32));     // 25.6 MB
  float* alpha1 = (float*)take((size_t)E * sizeof(float));           // 1.6 MB
  u16*   zb     = (u16*)  take((size_t)N * HF * sizeof(u16));        // 25.6 MB
  u16*   A2     = (u16*)  take((size_t)N * 2 * HF * sizeof(u16));    // 51.2 MB
  u16*   B2     = (u16*)  take((size_t)HF * 2 * HF * sizeof(u16));   // 1.05 MB

  rowstart_kernel<<<dim3((N + 1 + 255) / 256), 256, 0, stream>>>(dst, rs, N, E);

  const dim3 gemmGrid(HF / 64, (N + 127) / 128);   // 8 x 196 = 1568 blocks
  const dim3 nh8Grid((N * 8 + 255) / 256);

  // ---- Layer 1: K'=512 ----
  split_kernel<true ><<<dim3((N * K1 + 255) / 256), 256, 0, stream>>>(h,  A2, N * K1, K1);
  split_kernel<false><<<dim3((HF * K1 + 255) / 256), 256, 0, stream>>>(W1, B2, HF * K1, K1);
  gemm_bt_kernel<64, 1><<<gemmGrid, 256, 0, stream>>>(A2, B2, nullptr, zb, N, HF, 2 * K1, 2 * K1);
  elr_bf16_kernel<<<nh8Grid, 256, 0, stream>>>(zb, al1, ar1, el, er, N);
  alpha_kernel<<<nh8Grid, 256, 0, stream>>>(el, er, src, rs, edata, N, E);
  agg_sliced_kernel<<<dim3(N * 8), 64, 0, stream>>>(zb, edata, rs, A2, E);

  // ---- Layer 2: K'=1024 ----
  split_kernel<false><<<dim3((HF * HF + 255) / 256), 256, 0, stream>>>(W2, B2, HF * HF, HF);
  gemm_bt_kernel<64, 1><<<gemmGrid, 256, 0, stream>>>(A2, B2, nullptr, zb, N, HF, 2 * HF, 2 * HF);
  elr_bf16_kernel<<<nh8Grid, 256, 0, stream>>>(zb, al2, ar2, el, er, N);
  alpha_kernel<<<nh8Grid, 256, 0, stream>>>(el, er, src, rs, edata, N, E);
  agg_sliced_kernel<<<dim3(N * 8), 64, 0, stream>>>(zb, edata, rs, A2, E);

  // ---- Layer 3: K'=1024, Nout=32, split-K=4 + atomicAdd ----
  split_kernel<false><<<dim3((CLS * HF + 255) / 256), 256, 0, stream>>>(W3, B2, CLS * HF, HF);
  zero_kernel<<<dim3((N * CLS + 255) / 256), 256, 0, stream>>>(z3, N * CLS);
  gemm_bt_kernel<32, 2><<<dim3(4, (N + 127) / 128), 256, 0, stream>>>(A2, B2, z3, nullptr, N, CLS, 2 * HF, (2 * HF) / 4);
  elr_kernel<1, 32><<<dim3((N + 255) / 256), 256, 0, stream>>>(z3, al3, ar3, el, er, N);
  alpha1_kernel<<<dim3((N + 255) / 256), 256, 0, stream>>>(el, er, src, rs, alpha1, N);
  agg3_kernel<<<dim3(N), 64, 0, stream>>>(z3, alpha1, src, rs, out);
}

// Round 9
// 486.229 us; speedup vs baseline: 1.2664x; 1.2664x over previous
//
#include <hip/hip_runtime.h>
#include <cstdint>

#define DEVINL __device__ __forceinline__

typedef uint16_t u16;
typedef uint32_t u32;
typedef uint64_t u64;
typedef __attribute__((ext_vector_type(8))) short short8;
typedef __attribute__((ext_vector_type(4))) float floatx4;
typedef __attribute__((ext_vector_type(4))) u32 u32x4;
typedef __attribute__((ext_vector_type(2))) u32 u32x2;
typedef const __attribute__((address_space(1))) void* gas_ptr;
typedef __attribute__((address_space(3))) void* las_ptr;

DEVINL u16 f2bf(float f) {
  u32 u = __float_as_uint(f);
  u32 r = u + 0x7FFFu + ((u >> 16) & 1u);   // RNE
  return (u16)(r >> 16);
}
DEVINL float bf2f(u16 b) { return __uint_as_float((u32)b << 16); }
DEVINL float bf_lo(u32 u) { return __uint_as_float(u << 16); }
DEVINL float bf_hi(u32 u) { return __uint_as_float(u & 0xFFFF0000u); }

// ---------- row_start[n] = lower_bound(dst, n) over sorted dst ----------
__global__ void rowstart_kernel(const int* __restrict__ dst, int* __restrict__ rs,
                                int N, int E) {
  int n = blockIdx.x * blockDim.x + threadIdx.x;
  if (n > N) return;
  int lo = 0, hi = E;
  while (lo < hi) { int mid = (lo + hi) >> 1; if (dst[mid] < n) lo = mid + 1; else hi = mid; }
  rs[n] = lo;
}

__global__ void zero_kernel(float* __restrict__ p, int n) {
  int i = blockIdx.x * blockDim.x + threadIdx.x;
  if (i < n) p[i] = 0.f;
}

// ---------- f32 -> 2-plane split-bf16: A'=[hi|lo], B'=[hi|hi], row len 2K ----------
template<bool IsA>
__global__ __launch_bounds__(256)
void split_kernel(const float* __restrict__ in, u16* __restrict__ out, int MK, int K) {
  int idx = blockIdx.x * blockDim.x + threadIdx.x;
  if (idx >= MK) return;
  int m = idx / K, k = idx - m * K;
  float a = in[idx];
  u16 h = f2bf(a);
  size_t base = (size_t)m * 2 * K;
  if (IsA) {
    u16 lo = f2bf(a - bf2f(h));
    out[base + k] = h;  out[base + K + k] = lo;
  } else {
    out[base + k] = h;  out[base + K + k] = h;
  }
}

// ---------- GEMM: C[M,Nout] = A'[M,K'] * B'[Nout,K']^T  (split-bf16 in) ----------
// OUTM: 1 = bf16 store, 2 = f32 atomicAdd (split-K: blockIdx.x indexes K-chunk).
template<int BN, int OUTM>
__global__ __launch_bounds__(256)
void gemm_bt_kernel(const u16* __restrict__ A, const u16* __restrict__ B,
                    float* __restrict__ Cf, u16* __restrict__ Cb,
                    int M, int Nout, int K, int kLen)
{
  constexpr int BM = 128, BK = 32, CF = BN / 16;
  constexpr int BCALLS = (BN * BK) / 512;          // 8/4/2 for BN=128/64/32
  __shared__ __align__(16) u16 As[BM * BK];
  __shared__ __align__(16) u16 Bs[BN * BK];
  const int tid  = threadIdx.x;
  const int wave = tid >> 6;
  const int lane = tid & 63;
  const int quad = lane >> 4;
  const int l16  = lane & 15;
  const int rowBase = blockIdx.y * BM;
  const int colBase = (OUTM == 2) ? 0 : blockIdx.x * BN;
  const int kStart  = (OUTM == 2) ? blockIdx.x * kLen : 0;

  floatx4 acc[2][CF];
  #pragma unroll
  for (int r = 0; r < 2; ++r)
    #pragma unroll
    for (int c = 0; c < CF; ++c)
      acc[r][c] = (floatx4){0.f, 0.f, 0.f, 0.f};

  int aRow[2], aCol[2];
  #pragma unroll
  for (int i = 0; i < 2; ++i) {
    int call = wave + 4 * i;
    int flat = call * 512 + lane * 8;
    int r = flat >> 5;
    aCol[i] = flat & 31;
    int gr = rowBase + r;
    if (gr >= M) gr = M - 1;
    aRow[i] = gr;
  }
  int bRow[2] = {0, 0}, bCol[2] = {0, 0};
  #pragma unroll
  for (int i = 0; i < 2; ++i) {
    int call = wave + 4 * i;
    if (call < BCALLS) {
      int flat = call * 512 + lane * 8;
      bRow[i] = colBase + (flat >> 5);
      bCol[i] = flat & 31;
    }
  }

  for (int k0 = kStart; k0 < kStart + kLen; k0 += BK) {
    __syncthreads();
    #pragma unroll
    for (int i = 0; i < 2; ++i) {
      int call = wave + 4 * i;
      const u16* gp = A + (size_t)aRow[i] * K + (k0 + aCol[i]);
      __builtin_amdgcn_global_load_lds((gas_ptr)gp,
          (las_ptr)(As + call * 512), 16, 0, 0);
    }
    #pragma unroll
    for (int i = 0; i < 2; ++i) {
      int call = wave + 4 * i;
      if (call < BCALLS) {
        const u16* gp = B + (size_t)bRow[i] * K + (k0 + bCol[i]);
        __builtin_amdgcn_global_load_lds((gas_ptr)gp,
            (las_ptr)(Bs + call * 512), 16, 0, 0);
      }
    }
    __syncthreads();
    short8 a0 = *(const short8*)(As + (32 * wave + l16) * BK + quad * 8);
    short8 a1 = *(const short8*)(As + (32 * wave + 16 + l16) * BK + quad * 8);
    #pragma unroll
    for (int c = 0; c < CF; ++c) {
      short8 b = *(const short8*)(Bs + (16 * c + l16) * BK + quad * 8);
      acc[0][c] = __builtin_amdgcn_mfma_f32_16x16x32_bf16(a0, b, acc[0][c], 0, 0, 0);
      acc[1][c] = __builtin_amdgcn_mfma_f32_16x16x32_bf16(a1, b, acc[1][c], 0, 0, 0);
    }
  }

  // C/D layout: col = lane&15, row = quad*4 + reg (verified m89/m91)
  #pragma unroll
  for (int rt = 0; rt < 2; ++rt)
    #pragma unroll
    for (int c = 0; c < CF; ++c)
      #pragma unroll
      for (int i = 0; i < 4; ++i) {
        int gr = rowBase + 32 * wave + 16 * rt + quad * 4 + i;
        if (gr < M) {
          int gc = colBase + 16 * c + l16;
          if (OUTM == 1) Cb[(size_t)gr * Nout + gc] = f2bf(acc[rt][c][i]);
          else           atomicAdd(Cf + (size_t)gr * Nout + gc, acc[rt][c][i]);
        }
      }
}

// ---------- el/er from bf16 z (H=8, F=64) ----------
__global__ __launch_bounds__(256)
void elr_bf16_kernel(const u16* __restrict__ z, const float* __restrict__ al,
                     const float* __restrict__ ar, float* __restrict__ el,
                     float* __restrict__ er, int N)
{
  int t = blockIdx.x * blockDim.x + threadIdx.x;
  if (t >= N * 8) return;
  int h = t & 7;
  const u32x4* zp = (const u32x4*)(z + (size_t)t * 64);
  const float* alp = al + h * 64;
  const float* arp = ar + h * 64;
  float sl = 0.f, sr = 0.f;
  #pragma unroll
  for (int i = 0; i < 8; ++i) {
    u32x4 zz = zp[i];
    #pragma unroll
    for (int j = 0; j < 4; ++j) {
      float z0 = bf_lo(zz[j]), z1 = bf_hi(zz[j]);
      int f = i * 8 + 2 * j;
      sl += z0 * alp[f] + z1 * alp[f + 1];
      sr += z0 * arp[f] + z1 * arp[f + 1];
    }
  }
  el[t] = sl;
  er[t] = sr;
}

// ---------- f32 elr (layer 3, H=1, F=32) ----------
template<int H, int F>
__global__ __launch_bounds__(256)
void elr_kernel(const float* __restrict__ z, const float* __restrict__ al,
                const float* __restrict__ ar, float* __restrict__ el,
                float* __restrict__ er, int N)
{
  int t = blockIdx.x * blockDim.x + threadIdx.x;
  if (t >= N * H) return;
  int h = t % H;
  const float4* zp  = (const float4*)(z + (size_t)t * F);
  const float4* alp = (const float4*)(al + h * F);
  const float4* arp = (const float4*)(ar + h * F);
  float sl = 0.f, sr = 0.f;
  #pragma unroll
  for (int i = 0; i < F / 4; ++i) {
    float4 zz = zp[i], aa = alp[i], rr = arp[i];
    sl += zz.x * aa.x + zz.y * aa.y + zz.z * aa.z + zz.w * aa.w;
    sr += zz.x * rr.x + zz.y * rr.y + zz.z * rr.z + zz.w * rr.w;
  }
  el[t] = sl;
  er[t] = sr;
}

// ---------- edge-parallel UNNORMALIZED attention records ----------
// edata[h][e] = {src[e], w}, w = exp(leaky_relu(el[src,h]+er[dst,h])).
// blockIdx.y = h; consecutive lanes -> consecutive e -> fully coalesced 8B writes.
// Softmax normalization deferred to agg (shift-free: logits O(1), no overflow).
template<int H>
__global__ __launch_bounds__(256)
void alpha_kernel(const float* __restrict__ el, const float* __restrict__ er,
                  const int* __restrict__ src, const int* __restrict__ dst,
                  u32* __restrict__ edata, int E)
{
  int e = blockIdx.x * 256 + threadIdx.x;
  if (e >= E) return;
  int h = blockIdx.y;
  int si = src[e], di = dst[e];
  float v = el[si * H + h] + er[di * H + h];
  v = (v > 0.f) ? v : 0.2f * v;            // leaky_relu 0.2
  u32x2 ed;
  ed[0] = (u32)si;
  ed[1] = __float_as_uint(__expf(v));
  *(u32x2*)(edata + ((size_t)h * E + e) * 2) = ed;
}

// ---------- layers 1/2 aggregate, XCD-sliced, multi-node blocks ----------
// grid.x = 8 * ceil(N/16); h = bid&7 (one XCD per head slice: z slice 3.2 MB +
// edata plane 3.2 MB L2-resident). 256 threads = 16 quarters; each quarter
// (16 lanes, 8 B/lane = one 64-col z row) owns ONE node -> no cross-lane
// reduction, no shfl. den accumulated in-loop (records are unnormalized).
__global__ __launch_bounds__(256)
void agg_sliced_kernel(const u16* __restrict__ z, const u32* __restrict__ edata,
                       const int* __restrict__ rs, u16* __restrict__ a2out,
                       int N, int E)
{
  const int bid = blockIdx.x;
  const int h = bid & 7;                   // slice == head == XCD
  const int tid = threadIdx.x;
  const int n = (bid >> 3) * 16 + (tid >> 4);
  const int c = tid & 15;                  // col group: 4 bf16 cols = 8 B
  if (n >= N) return;
  const int s = rs[n], e = rs[n + 1];
  const u16* zs = z + h * 64 + 4 * c;
  const u32* eb = edata + (size_t)h * E * 2;

  float a0 = 0.f, a1 = 0.f, a2 = 0.f, a3 = 0.f, den = 0.f;

  for (int k0 = s; k0 < e; k0 += 2) {
    #pragma unroll
    for (int j = 0; j < 2; ++j) {
      int k = k0 + j;
      int kc = min(k, e - 1);              // clamp: safe load, zero weight
      u32x2 ed = *(const u32x2*)(eb + (size_t)kc * 2);   // broadcast {src, w}
      int si = (int)ed[0];
      float aw = (k < e) ? __uint_as_float(ed[1]) : 0.f;
      u32x2 zz = *(const u32x2*)(zs + (size_t)si * 512); // L2-hit gather
      a0 += aw * bf_lo(zz[0]);
      a1 += aw * bf_hi(zz[0]);
      a2 += aw * bf_lo(zz[1]);
      a3 += aw * bf_hi(zz[1]);
      den += aw;
    }
  }

  const float r = (e > s) ? (1.f / den) : 0.f;   // deg==0 -> zeros
  float o[4] = {a0 * r, a1 * r, a2 * r, a3 * r};
  u32x2 hp, lp;
  #pragma unroll
  for (int j = 0; j < 2; ++j) {
    float o0 = o[2 * j], o1 = o[2 * j + 1];
    o0 = (o0 > 0.f) ? o0 : (__expf(o0) - 1.f);   // elu
    o1 = (o1 > 0.f) ? o1 : (__expf(o1) - 1.f);
    u16 h0 = f2bf(o0), h1 = f2bf(o1);
    u16 l0 = f2bf(o0 - bf2f(h0)), l1 = f2bf(o1 - bf2f(h1));
    hp[j] = ((u32)h1 << 16) | h0;
    lp[j] = ((u32)l1 << 16) | l0;
  }
  u16* row = a2out + (size_t)n * 1024 + h * 64 + 4 * c;  // A' = [hi|lo]
  *(u32x2*)row = hp;
  *(u32x2*)(row + 512) = lp;
}

// ---------- layer 3 aggregate: f32 z3 (3.2 MB), 8 nodes/block ----------
__global__ __launch_bounds__(256)
void agg3_kernel(const float* __restrict__ z, const u32* __restrict__ edata,
                 const int* __restrict__ rs, float* __restrict__ out, int N)
{
  const int tid = threadIdx.x;
  const int n = blockIdx.x * 8 + (tid >> 5);
  const int c = tid & 31;
  if (n >= N) return;
  const int s = rs[n], e = rs[n + 1];
  float acc = 0.f, den = 0.f;

  for (int k0 = s; k0 < e; k0 += 2) {
    #pragma unroll
    for (int j = 0; j < 2; ++j) {
      int k = k0 + j;
      int kc = min(k, e - 1);
      u32x2 ed = *(const u32x2*)(edata + (size_t)kc * 2);
      int si = (int)ed[0];
      float aw = (k < e) ? __uint_as_float(ed[1]) : 0.f;
      acc += aw * z[(size_t)si * 32 + c];
      den += aw;
    }
  }
  out[(size_t)n * 32 + c] = (e > s) ? (acc / den) : 0.f;
}

extern "C" void kernel_launch(void* const* d_in, const int* in_sizes, int n_in,
                              void* d_out, int out_size, void* d_ws, size_t ws_size,
                              hipStream_t stream)
{
  constexpr int N = 25000, E = 400000, K1 = 256, HF = 512, CLS = 32;
  const float* h   = (const float*)d_in[0];
  const int*   src = (const int*)d_in[1];
  const int*   dst = (const int*)d_in[2];
  const float* W1  = (const float*)d_in[3];
  const float* al1 = (const float*)d_in[4];
  const float* ar1 = (const float*)d_in[5];
  const float* W2  = (const float*)d_in[6];
  const float* al2 = (const float*)d_in[7];
  const float* ar2 = (const float*)d_in[8];
  const float* W3  = (const float*)d_in[9];
  const float* al3 = (const float*)d_in[10];
  const float* ar3 = (const float*)d_in[11];
  float* out = (float*)d_out;

  char* w = (char*)d_ws;
  auto take = [&](size_t bytes) {
    char* p = w;
    w += (bytes + 255) & ~(size_t)255;
    return p;
  };
  int*   rs     = (int*)  take((size_t)(N + 1) * sizeof(int));
  float* el     = (float*)take((size_t)N * 8 * sizeof(float));
  float* er     = (float*)take((size_t)N * 8 * sizeof(float));
  float* z3     = (float*)take((size_t)N * CLS * sizeof(float));     // 3.2 MB
  u32*   edata  = (u32*)  take((size_t)E * 8 * 2 * sizeof(u32));     // 25.6 MB
  u32*   edata1 = (u32*)  take((size_t)E * 2 * sizeof(u32));         // 3.2 MB
  u16*   zb     = (u16*)  take((size_t)N * HF * sizeof(u16));        // 25.6 MB
  u16*   A2     = (u16*)  take((size_t)N * 2 * HF * sizeof(u16));    // 51.2 MB
  u16*   B2     = (u16*)  take((size_t)HF * 2 * HF * sizeof(u16));   // 1.05 MB

  rowstart_kernel<<<dim3((N + 1 + 255) / 256), 256, 0, stream>>>(dst, rs, N, E);

  const dim3 gemmGrid(HF / 64, (N + 127) / 128);   // 8 x 196 = 1568 blocks
  const dim3 nh8Grid((N * 8 + 255) / 256);
  const dim3 alphaGrid((E + 255) / 256, 8);
  const dim3 aggGrid(8 * ((N + 15) / 16));

  // ---- Layer 1: K'=512 ----
  split_kernel<true ><<<dim3((N * K1 + 255) / 256), 256, 0, stream>>>(h,  A2, N * K1, K1);
  split_kernel<false><<<dim3((HF * K1 + 255) / 256), 256, 0, stream>>>(W1, B2, HF * K1, K1);
  gemm_bt_kernel<64, 1><<<gemmGrid, 256, 0, stream>>>(A2, B2, nullptr, zb, N, HF, 2 * K1, 2 * K1);
  elr_bf16_kernel<<<nh8Grid, 256, 0, stream>>>(zb, al1, ar1, el, er, N);
  alpha_kernel<8><<<alphaGrid, 256, 0, stream>>>(el, er, src, dst, edata, E);
  agg_sliced_kernel<<<aggGrid, 256, 0, stream>>>(zb, edata, rs, A2, N, E);

  // ---- Layer 2: K'=1024 ----
  split_kernel<false><<<dim3((HF * HF + 255) / 256), 256, 0, stream>>>(W2, B2, HF * HF, HF);
  gemm_bt_kernel<64, 1><<<gemmGrid, 256, 0, stream>>>(A2, B2, nullptr, zb, N, HF, 2 * HF, 2 * HF);
  elr_bf16_kernel<<<nh8Grid, 256, 0, stream>>>(zb, al2, ar2, el, er, N);
  alpha_kernel<8><<<alphaGrid, 256, 0, stream>>>(el, er, src, dst, edata, E);
  agg_sliced_kernel<<<aggGrid, 256, 0, stream>>>(zb, edata, rs, A2, N, E);

  // ---- Layer 3: K'=1024, Nout=32, split-K=4 + atomicAdd ----
  split_kernel<false><<<dim3((CLS * HF + 255) / 256), 256, 0, stream>>>(W3, B2, CLS * HF, HF);
  zero_kernel<<<dim3((N * CLS + 255) / 256), 256, 0, stream>>>(z3, N * CLS);
  gemm_bt_kernel<32, 2><<<dim3(4, (N + 127) / 128), 256, 0, stream>>>(A2, B2, z3, nullptr, N, CLS, 2 * HF, (2 * HF) / 4);
  elr_kernel<1, 32><<<dim3((N + 255) / 256), 256, 0, stream>>>(z3, al3, ar3, el, er, N);
  alpha_kernel<1><<<dim3((E + 255) / 256, 1), 256, 0, stream>>>(el, er, src, dst, edata1, E);
  agg3_kernel<<<dim3((N + 7) / 8), 256, 0, stream>>>(z3, edata1, rs, out, N);
}

// Round 10
// 452.157 us; speedup vs baseline: 1.3618x; 1.0754x over previous
//
#include <hip/hip_runtime.h>
#include <cstdint>

#define DEVINL __device__ __forceinline__

typedef uint16_t u16;
typedef uint32_t u32;
typedef uint64_t u64;
typedef __attribute__((ext_vector_type(8))) short short8;
typedef __attribute__((ext_vector_type(4))) float floatx4;
typedef __attribute__((ext_vector_type(4))) u32 u32x4;
typedef __attribute__((ext_vector_type(2))) u32 u32x2;
typedef const __attribute__((address_space(1))) void* gas_ptr;
typedef __attribute__((address_space(3))) void* las_ptr;

DEVINL u16 f2bf(float f) {
  u32 u = __float_as_uint(f);
  u32 r = u + 0x7FFFu + ((u >> 16) & 1u);   // RNE
  return (u16)(r >> 16);
}
DEVINL float bf2f(u16 b) { return __uint_as_float((u32)b << 16); }
DEVINL float bf_lo(u32 u) { return __uint_as_float(u << 16); }
DEVINL float bf_hi(u32 u) { return __uint_as_float(u & 0xFFFF0000u); }

// ---------- row_start[n] = lower_bound(dst, n) over sorted dst ----------
__global__ void rowstart_kernel(const int* __restrict__ dst, int* __restrict__ rs,
                                int N, int E) {
  int n = blockIdx.x * blockDim.x + threadIdx.x;
  if (n > N) return;
  int lo = 0, hi = E;
  while (lo < hi) { int mid = (lo + hi) >> 1; if (dst[mid] < n) lo = mid + 1; else hi = mid; }
  rs[n] = lo;
}

__global__ void zero_kernel(float* __restrict__ p, int n) {
  int i = blockIdx.x * blockDim.x + threadIdx.x;
  if (i < n) p[i] = 0.f;
}

// ---------- f32 -> 2-plane split-bf16: A'=[hi|lo], B'=[hi|hi], row len 2K ----------
template<bool IsA>
__global__ __launch_bounds__(256)
void split_kernel(const float* __restrict__ in, u16* __restrict__ out, int MK, int K) {
  int idx = blockIdx.x * blockDim.x + threadIdx.x;
  if (idx >= MK) return;
  int m = idx / K, k = idx - m * K;
  float a = in[idx];
  u16 h = f2bf(a);
  size_t base = (size_t)m * 2 * K;
  if (IsA) {
    u16 lo = f2bf(a - bf2f(h));
    out[base + k] = h;  out[base + K + k] = lo;
  } else {
    out[base + k] = h;  out[base + K + k] = h;
  }
}

// ---------- GEMM: C[M,Nout] = A'[M,K'] * B'[Nout,K']^T  (split-bf16 in) ----------
// OUTM 1: bf16 store, 1-D grid (784 = 8 XCD * 98), XCD-swizzled so each XCD
//   owns a contiguous row-band range with ALL 4 column tiles co-resident ->
//   A fetched past-L2 once (compulsory), B L2-resident per XCD.
// OUTM 2: f32 atomicAdd split-K, 2-D grid (blockIdx.x = K-chunk).
template<int BN, int OUTM>
__global__ __launch_bounds__(256)
void gemm_bt_kernel(const u16* __restrict__ A, const u16* __restrict__ B,
                    float* __restrict__ Cf, u16* __restrict__ Cb,
                    int M, int Nout, int K, int kLen)
{
  constexpr int BM = 128, BK = 32, CF = BN / 16;
  constexpr int BCALLS = (BN * BK) / 512;          // 8 for BN=128, 2 for BN=32
  __shared__ __align__(16) u16 As[BM * BK];
  __shared__ __align__(16) u16 Bs[BN * BK];
  const int tid  = threadIdx.x;
  const int wave = tid >> 6;
  const int lane = tid & 63;
  const int quad = lane >> 4;
  const int l16  = lane & 15;

  int bxv, byv;
  if (OUTM == 1) {                       // XCD swizzle: xcd = g&7 owns 98 blocks
    int g = blockIdx.x;
    int perX = gridDim.x >> 3;           // 98
    int flat = (g & 7) * perX + (g >> 3);
    byv = flat >> 2;                     // 4 col-tiles (Nout=512 / BN=128)
    bxv = flat & 3;
  } else {
    bxv = blockIdx.x; byv = blockIdx.y;
  }
  const int rowBase = byv * BM;
  const int colBase = (OUTM == 2) ? 0 : bxv * BN;
  const int kStart  = (OUTM == 2) ? bxv * kLen : 0;

  floatx4 acc[2][CF];
  #pragma unroll
  for (int r = 0; r < 2; ++r)
    #pragma unroll
    for (int c = 0; c < CF; ++c)
      acc[r][c] = (floatx4){0.f, 0.f, 0.f, 0.f};

  int aRow[2], aCol[2];
  #pragma unroll
  for (int i = 0; i < 2; ++i) {
    int call = wave + 4 * i;
    int flat = call * 512 + lane * 8;
    int r = flat >> 5;
    aCol[i] = flat & 31;
    int gr = rowBase + r;
    if (gr >= M) gr = M - 1;             // clamp: safe load, store guarded
    aRow[i] = gr;
  }
  int bRow[2] = {0, 0}, bCol[2] = {0, 0};
  #pragma unroll
  for (int i = 0; i < 2; ++i) {
    int call = wave + 4 * i;
    if (call < BCALLS) {
      int flat = call * 512 + lane * 8;
      bRow[i] = colBase + (flat >> 5);
      bCol[i] = flat & 31;
    }
  }

  for (int k0 = kStart; k0 < kStart + kLen; k0 += BK) {
    __syncthreads();
    #pragma unroll
    for (int i = 0; i < 2; ++i) {
      int call = wave + 4 * i;
      const u16* gp = A + (size_t)aRow[i] * K + (k0 + aCol[i]);
      __builtin_amdgcn_global_load_lds((gas_ptr)gp,
          (las_ptr)(As + call * 512), 16, 0, 0);
    }
    #pragma unroll
    for (int i = 0; i < 2; ++i) {
      int call = wave + 4 * i;
      if (call < BCALLS) {
        const u16* gp = B + (size_t)bRow[i] * K + (k0 + bCol[i]);
        __builtin_amdgcn_global_load_lds((gas_ptr)gp,
            (las_ptr)(Bs + call * 512), 16, 0, 0);
      }
    }
    __syncthreads();
    short8 a0 = *(const short8*)(As + (32 * wave + l16) * BK + quad * 8);
    short8 a1 = *(const short8*)(As + (32 * wave + 16 + l16) * BK + quad * 8);
    #pragma unroll
    for (int c = 0; c < CF; ++c) {
      short8 b = *(const short8*)(Bs + (16 * c + l16) * BK + quad * 8);
      acc[0][c] = __builtin_amdgcn_mfma_f32_16x16x32_bf16(a0, b, acc[0][c], 0, 0, 0);
      acc[1][c] = __builtin_amdgcn_mfma_f32_16x16x32_bf16(a1, b, acc[1][c], 0, 0, 0);
    }
  }

  // C/D layout: col = lane&15, row = quad*4 + reg (verified m89/m91)
  #pragma unroll
  for (int rt = 0; rt < 2; ++rt)
    #pragma unroll
    for (int c = 0; c < CF; ++c)
      #pragma unroll
      for (int i = 0; i < 4; ++i) {
        int gr = rowBase + 32 * wave + 16 * rt + quad * 4 + i;
        if (gr < M) {
          int gc = colBase + 16 * c + l16;
          if (OUTM == 1) Cb[(size_t)gr * Nout + gc] = f2bf(acc[rt][c][i]);
          else           atomicAdd(Cf + (size_t)gr * Nout + gc, acc[rt][c][i]);
        }
      }
}

// ---------- el/er from bf16 z (H=8, F=64) ----------
__global__ __launch_bounds__(256)
void elr_bf16_kernel(const u16* __restrict__ z, const float* __restrict__ al,
                     const float* __restrict__ ar, float* __restrict__ el,
                     float* __restrict__ er, int N)
{
  int t = blockIdx.x * blockDim.x + threadIdx.x;
  if (t >= N * 8) return;
  int h = t & 7;
  const u32x4* zp = (const u32x4*)(z + (size_t)t * 64);
  const float* alp = al + h * 64;
  const float* arp = ar + h * 64;
  float sl = 0.f, sr = 0.f;
  #pragma unroll
  for (int i = 0; i < 8; ++i) {
    u32x4 zz = zp[i];
    #pragma unroll
    for (int j = 0; j < 4; ++j) {
      float z0 = bf_lo(zz[j]), z1 = bf_hi(zz[j]);
      int f = i * 8 + 2 * j;
      sl += z0 * alp[f] + z1 * alp[f + 1];
      sr += z0 * arp[f] + z1 * arp[f + 1];
    }
  }
  el[t] = sl;
  er[t] = sr;
}

// ---------- f32 elr (layer 3, H=1, F=32) ----------
template<int H, int F>
__global__ __launch_bounds__(256)
void elr_kernel(const float* __restrict__ z, const float* __restrict__ al,
                const float* __restrict__ ar, float* __restrict__ el,
                float* __restrict__ er, int N)
{
  int t = blockIdx.x * blockDim.x + threadIdx.x;
  if (t >= N * H) return;
  int h = t % H;
  const float4* zp  = (const float4*)(z + (size_t)t * F);
  const float4* alp = (const float4*)(al + h * F);
  const float4* arp = (const float4*)(ar + h * F);
  float sl = 0.f, sr = 0.f;
  #pragma unroll
  for (int i = 0; i < F / 4; ++i) {
    float4 zz = zp[i], aa = alp[i], rr = arp[i];
    sl += zz.x * aa.x + zz.y * aa.y + zz.z * aa.z + zz.w * aa.w;
    sr += zz.x * rr.x + zz.y * rr.y + zz.z * rr.z + zz.w * rr.w;
  }
  el[t] = sl;
  er[t] = sr;
}

// ---------- edge-parallel UNNORMALIZED attention records ----------
// edata[h][e] = {src[e], w}, w = exp(leaky_relu(el[src,h]+er[dst,h])).
// blockIdx.y = h; consecutive lanes -> consecutive e -> fully coalesced 8B writes.
// Softmax normalization deferred to agg (shift-free: logits O(1), no overflow).
template<int H>
__global__ __launch_bounds__(256)
void alpha_kernel(const float* __restrict__ el, const float* __restrict__ er,
                  const int* __restrict__ src, const int* __restrict__ dst,
                  u32* __restrict__ edata, int E)
{
  int e = blockIdx.x * 256 + threadIdx.x;
  if (e >= E) return;
  int h = blockIdx.y;
  int si = src[e], di = dst[e];
  float v = el[si * H + h] + er[di * H + h];
  v = (v > 0.f) ? v : 0.2f * v;            // leaky_relu 0.2
  u32x2 ed;
  ed[0] = (u32)si;
  ed[1] = __float_as_uint(__expf(v));
  *(u32x2*)(edata + ((size_t)h * E + e) * 2) = ed;
}

// ---------- layers 1/2 aggregate, XCD-sliced, multi-node blocks ----------
// grid.x = 8 * ceil(N/16); h = bid&7 (one XCD per head slice: z slice 3.2 MB +
// edata plane 3.2 MB L2-resident). 256 threads = 16 quarters; each quarter
// (16 lanes, 8 B/lane = one 64-col z row) owns ONE node -> no cross-lane
// reduction, no shfl. den accumulated in-loop (records are unnormalized).
__global__ __launch_bounds__(256)
void agg_sliced_kernel(const u16* __restrict__ z, const u32* __restrict__ edata,
                       const int* __restrict__ rs, u16* __restrict__ a2out,
                       int N, int E)
{
  const int bid = blockIdx.x;
  const int h = bid & 7;                   // slice == head == XCD
  const int tid = threadIdx.x;
  const int n = (bid >> 3) * 16 + (tid >> 4);
  const int c = tid & 15;                  // col group: 4 bf16 cols = 8 B
  if (n >= N) return;
  const int s = rs[n], e = rs[n + 1];
  const u16* zs = z + h * 64 + 4 * c;
  const u32* eb = edata + (size_t)h * E * 2;

  float a0 = 0.f, a1 = 0.f, a2 = 0.f, a3 = 0.f, den = 0.f;

  for (int k0 = s; k0 < e; k0 += 2) {
    #pragma unroll
    for (int j = 0; j < 2; ++j) {
      int k = k0 + j;
      int kc = min(k, e - 1);              // clamp: safe load, zero weight
      u32x2 ed = *(const u32x2*)(eb + (size_t)kc * 2);   // broadcast {src, w}
      int si = (int)ed[0];
      float aw = (k < e) ? __uint_as_float(ed[1]) : 0.f;
      u32x2 zz = *(const u32x2*)(zs + (size_t)si * 512); // L2-hit gather
      a0 += aw * bf_lo(zz[0]);
      a1 += aw * bf_hi(zz[0]);
      a2 += aw * bf_lo(zz[1]);
      a3 += aw * bf_hi(zz[1]);
      den += aw;
    }
  }

  const float r = (e > s) ? (1.f / den) : 0.f;   // deg==0 -> zeros
  float o[4] = {a0 * r, a1 * r, a2 * r, a3 * r};
  u32x2 hp, lp;
  #pragma unroll
  for (int j = 0; j < 2; ++j) {
    float o0 = o[2 * j], o1 = o[2 * j + 1];
    o0 = (o0 > 0.f) ? o0 : (__expf(o0) - 1.f);   // elu
    o1 = (o1 > 0.f) ? o1 : (__expf(o1) - 1.f);
    u16 h0 = f2bf(o0), h1 = f2bf(o1);
    u16 l0 = f2bf(o0 - bf2f(h0)), l1 = f2bf(o1 - bf2f(h1));
    hp[j] = ((u32)h1 << 16) | h0;
    lp[j] = ((u32)l1 << 16) | l0;
  }
  u16* row = a2out + (size_t)n * 1024 + h * 64 + 4 * c;  // A' = [hi|lo]
  *(u32x2*)row = hp;
  *(u32x2*)(row + 512) = lp;
}

// ---------- layer 3 aggregate: f32 z3 (3.2 MB), 8 nodes/block ----------
__global__ __launch_bounds__(256)
void agg3_kernel(const float* __restrict__ z, const u32* __restrict__ edata,
                 const int* __restrict__ rs, float* __restrict__ out, int N)
{
  const int tid = threadIdx.x;
  const int n = blockIdx.x * 8 + (tid >> 5);
  const int c = tid & 31;
  if (n >= N) return;
  const int s = rs[n], e = rs[n + 1];
  float acc = 0.f, den = 0.f;

  for (int k0 = s; k0 < e; k0 += 2) {
    #pragma unroll
    for (int j = 0; j < 2; ++j) {
      int k = k0 + j;
      int kc = min(k, e - 1);
      u32x2 ed = *(const u32x2*)(edata + (size_t)kc * 2);
      int si = (int)ed[0];
      float aw = (k < e) ? __uint_as_float(ed[1]) : 0.f;
      acc += aw * z[(size_t)si * 32 + c];
      den += aw;
    }
  }
  out[(size_t)n * 32 + c] = (e > s) ? (acc / den) : 0.f;
}

extern "C" void kernel_launch(void* const* d_in, const int* in_sizes, int n_in,
                              void* d_out, int out_size, void* d_ws, size_t ws_size,
                              hipStream_t stream)
{
  constexpr int N = 25000, E = 400000, K1 = 256, HF = 512, CLS = 32;
  const float* h   = (const float*)d_in[0];
  const int*   src = (const int*)d_in[1];
  const int*   dst = (const int*)d_in[2];
  const float* W1  = (const float*)d_in[3];
  const float* al1 = (const float*)d_in[4];
  const float* ar1 = (const float*)d_in[5];
  const float* W2  = (const float*)d_in[6];
  const float* al2 = (const float*)d_in[7];
  const float* ar2 = (const float*)d_in[8];
  const float* W3  = (const float*)d_in[9];
  const float* al3 = (const float*)d_in[10];
  const float* ar3 = (const float*)d_in[11];
  float* out = (float*)d_out;

  char* w = (char*)d_ws;
  auto take = [&](size_t bytes) {
    char* p = w;
    w += (bytes + 255) & ~(size_t)255;
    return p;
  };
  int*   rs     = (int*)  take((size_t)(N + 1) * sizeof(int));
  float* el     = (float*)take((size_t)N * 8 * sizeof(float));
  float* er     = (float*)take((size_t)N * 8 * sizeof(float));
  float* z3     = (float*)take((size_t)N * CLS * sizeof(float));     // 3.2 MB
  u32*   edata  = (u32*)  take((size_t)E * 8 * 2 * sizeof(u32));     // 25.6 MB
  u32*   edata1 = (u32*)  take((size_t)E * 2 * sizeof(u32));         // 3.2 MB
  u16*   zb     = (u16*)  take((size_t)N * HF * sizeof(u16));        // 25.6 MB
  u16*   A2     = (u16*)  take((size_t)N * 2 * HF * sizeof(u16));    // 51.2 MB
  u16*   B2     = (u16*)  take((size_t)HF * 2 * HF * sizeof(u16));   // 1.05 MB

  rowstart_kernel<<<dim3((N + 1 + 255) / 256), 256, 0, stream>>>(dst, rs, N, E);

  const dim3 gemmGrid(8 * 98);                     // 784 blocks, XCD-swizzled in-kernel
  const dim3 nh8Grid((N * 8 + 255) / 256);
  const dim3 alphaGrid((E + 255) / 256, 8);
  const dim3 aggGrid(8 * ((N + 15) / 16));

  // ---- Layer 1: K'=512 ----
  split_kernel<true ><<<dim3((N * K1 + 255) / 256), 256, 0, stream>>>(h,  A2, N * K1, K1);
  split_kernel<false><<<dim3((HF * K1 + 255) / 256), 256, 0, stream>>>(W1, B2, HF * K1, K1);
  gemm_bt_kernel<128, 1><<<gemmGrid, 256, 0, stream>>>(A2, B2, nullptr, zb, N, HF, 2 * K1, 2 * K1);
  elr_bf16_kernel<<<nh8Grid, 256, 0, stream>>>(zb, al1, ar1, el, er, N);
  alpha_kernel<8><<<alphaGrid, 256, 0, stream>>>(el, er, src, dst, edata, E);
  agg_sliced_kernel<<<aggGrid, 256, 0, stream>>>(zb, edata, rs, A2, N, E);

  // ---- Layer 2: K'=1024 ----
  split_kernel<false><<<dim3((HF * HF + 255) / 256), 256, 0, stream>>>(W2, B2, HF * HF, HF);
  gemm_bt_kernel<128, 1><<<gemmGrid, 256, 0, stream>>>(A2, B2, nullptr, zb, N, HF, 2 * HF, 2 * HF);
  elr_bf16_kernel<<<nh8Grid, 256, 0, stream>>>(zb, al2, ar2, el, er, N);
  alpha_kernel<8><<<alphaGrid, 256, 0, stream>>>(el, er, src, dst, edata, E);
  agg_sliced_kernel<<<aggGrid, 256, 0, stream>>>(zb, edata, rs, A2, N, E);

  // ---- Layer 3: K'=1024, Nout=32, split-K=4 + atomicAdd ----
  split_kernel<false><<<dim3((CLS * HF + 255) / 256), 256, 0, stream>>>(W3, B2, CLS * HF, HF);
  zero_kernel<<<dim3((N * CLS + 255) / 256), 256, 0, stream>>>(z3, N * CLS);
  gemm_bt_kernel<32, 2><<<dim3(4, (N + 127) / 128), 256, 0, stream>>>(A2, B2, z3, nullptr, N, CLS, 2 * HF, (2 * HF) / 4);
  elr_kernel<1, 32><<<dim3((N + 255) / 256), 256, 0, stream>>>(z3, al3, ar3, el, er, N);
  alpha_kernel<1><<<dim3((E + 255) / 256, 1), 256, 0, stream>>>(el, er, src, dst, edata1, E);
  agg3_kernel<<<dim3((N + 7) / 8), 256, 0, stream>>>(z3, edata1, rs, out, N);
}